// Round 1
// baseline (69.433 us; speedup 1.0000x reference)
//
#include <hip/hip_runtime.h>

#define C_IN     7
#define D_MODEL  512
#define TAO      3
#define M_TAPS   5
#define KERNELS  73            // D_MODEL / C_IN
#define B_SZ     32
#define L_SZ     4096
#define TB       64            // t-positions per block
#define NTB      (L_SZ / TB)   // 64
#define ROWS     (TB + 17)     // 81 staged rows (16 back-halo + 1 forward)
#define RPAD     84

__global__ __launch_bounds__(512, 4) void trc_conv_kernel(
    const float* __restrict__ x,          // [B, L, C_IN]
    const float* __restrict__ conv_w,     // [73, 6, 3]
    const float* __restrict__ conv_b,     // [73]
    const float* __restrict__ leftout_w,  // [1, 6, 3]
    const float* __restrict__ leftout_b,  // [1]
    float* __restrict__ out)              // [B, L, 512]
{
    __shared__ float xs[C_IN][RPAD];
    const int tid = threadIdx.x;
    const int b   = blockIdx.x / NTB;
    const int tb  = blockIdx.x % NTB;
    const int t0  = tb * TB;

    // Stage x rows [t0-16, t0+TB] (circular) into LDS, transposed [ch][row].
    const float* xb = x + (size_t)b * L_SZ * C_IN;
    for (int i = tid; i < ROWS * C_IN; i += 512) {
        int r = i / C_IN, c = i - r * C_IN;
        int g = t0 - 16 + r;
        if (g < 0)      g += L_SZ;
        if (g >= L_SZ)  g -= L_SZ;
        xs[c][r] = xb[(size_t)g * C_IN + c];
    }
    __syncthreads();

    // Per-thread output column d: ch = d/73, o = d%73 (d==511 -> leftout).
    const int d = tid;
    int ch;
    const float* wsrc;
    float bias;
    if (d < C_IN * KERNELS) {
        ch = d / KERNELS;
        int o = d - ch * KERNELS;
        wsrc = conv_w + o * 18;
        bias = conv_b[o];
    } else {
        ch = C_IN - 1;
        wsrc = leftout_w;
        bias = leftout_b[0];
    }

    // FIR weights by row-offset j (0 = oldest = row t-16): k=j%3, m=(15+k-j)/3.
    float wreg[18];
    #pragma unroll
    for (int j = 0; j < 18; ++j) {
        int k = j % 3;
        int m = (15 + k - j) / 3;
        wreg[j] = wsrc[m * 3 + k];
    }

    float* outp = out + ((size_t)b * L_SZ + t0) * D_MODEL + d;

    if (tb != 0 && tb != NTB - 1) {
        // Interior tile: every t in [16, 4094] -> pure 18-tap FIR,
        // sliding register window, 1 LDS read per output.
        float win[18];
        #pragma unroll
        for (int j = 0; j < 17; ++j) win[j] = xs[ch][j];
        #pragma unroll
        for (int tl = 0; tl < TB; ++tl) {
            win[(tl + 17) % 18] = xs[ch][tl + 17];
            float acc = bias;
            #pragma unroll
            for (int j = 0; j < 18; ++j)
                acc = fmaf(win[(tl + j) % 18], wreg[j], acc);
            outp[(size_t)tl * D_MODEL] = acc;
        }
    } else {
        // Edge tiles: per-k wrap + validity (tt >= 15) masking.
        for (int tl = 0; tl < TB; ++tl) {
            int t = t0 + tl;
            float acc = bias;
            #pragma unroll
            for (int k = 0; k < 3; ++k) {
                int tt = t + k - 1;
                if (tt < 0)      tt += L_SZ;
                if (tt >= L_SZ)  tt -= L_SZ;
                if (tt >= M_TAPS * TAO) {
                    int lt = tl + 15 + k;
                    #pragma unroll
                    for (int m = 0; m < 6; ++m)
                        acc = fmaf(xs[ch][lt - 3 * m], wreg[15 + k - 3 * m], acc);
                }
            }
            outp[(size_t)tl * D_MODEL] = acc;
        }
    }
}

extern "C" void kernel_launch(void* const* d_in, const int* in_sizes, int n_in,
                              void* d_out, int out_size, void* d_ws, size_t ws_size,
                              hipStream_t stream) {
    const float* x          = (const float*)d_in[0];
    const float* conv_w     = (const float*)d_in[1];
    const float* conv_b     = (const float*)d_in[2];
    const float* leftout_w  = (const float*)d_in[3];
    const float* leftout_b  = (const float*)d_in[4];
    float* out = (float*)d_out;

    dim3 grid(B_SZ * NTB);   // 2048 blocks
    trc_conv_kernel<<<grid, 512, 0, stream>>>(x, conv_w, conv_b,
                                              leftout_w, leftout_b, out);
}